// Round 5
// baseline (242.185 us; speedup 1.0000x reference)
//
#include <hip/hip_runtime.h>
#include <hip/hip_bf16.h>
#include <math.h>

#define D_MODEL 768
#define NHEADS  12
#define DHEAD   64
#define NQR     8     // query rows
#define BB      16    // batch (ranks)
#define PP      197   // tokens per rank
#define NPAIR   256   // BB*BB
#define MKV     (BB*PP)     // 3152
#define LN_EPSF 1e-5f
#define SCALEF  0.125f      // 64^-0.5

// split-bf16 K-extended GEMM params
#define KTOT  2304          // 3*768:  [a_hi|a_hi|a_lo] x [w_hi|w_lo|w_hi]
#define KSPLIT 3
#define KPER  (KTOT/KSPLIT) // 768
#define MPAD  3200          // 25*128
#define BM 128
#define BN 128
#define BK 64

typedef __attribute__((ext_vector_type(8))) short short8v;   // 8 bf16
typedef __attribute__((ext_vector_type(4))) float float4v;   // mfma acc

__device__ __forceinline__ void gload16(const void* g, void* l){
  __builtin_amdgcn_global_load_lds(
      (const __attribute__((address_space(1))) unsigned int*)g,
      (__attribute__((address_space(3))) unsigned int*)l, 16, 0, 0);
}

// ---------------------------------------------------------------------------
// fused pack + q-path.
// blocks [0, MPAD)               : pack kv_x rows -> Ab, layout [hi, hi, lo]
// blocks [MPAD, MPAD+768)        : pack kv_w rows -> Wb, layout [hi, lo, hi]
// blocks [MPAD+768, MPAD+768+8)  : q row r = b-(MPAD+768):
//                                  q_ln[r] = LN(q_x[r] @ q_w.T + q_b)*lnq_w+lnq_b
// ---------------------------------------------------------------------------
__global__ __launch_bounds__(192) void pack_q_kernel(
    const float* __restrict__ kvx, const float* __restrict__ kvw,
    __hip_bfloat16* __restrict__ Ab, __hip_bfloat16* __restrict__ Wb,
    const float* __restrict__ qx, const float* __restrict__ qw,
    const float* __restrict__ qb, const float* __restrict__ lnqw,
    const float* __restrict__ lnqb, float* __restrict__ qln)
{
  int b = blockIdx.x, t = threadIdx.x;
  if (b < MPAD + D_MODEL){
    const float* X; __hip_bfloat16* Y; int valid, mode, m;
    if (b < MPAD){ X = kvx; Y = Ab; valid = MKV;     mode = 0; m = b; }
    else         { X = kvw; Y = Wb; valid = D_MODEL; mode = 1; m = b - MPAD; }
    int k = t*4;
    float4 v = (m < valid) ? *(const float4*)&X[(size_t)m*D_MODEL + k]
                           : make_float4(0.f,0.f,0.f,0.f);
    float xsv[4] = {v.x, v.y, v.z, v.w};
    unsigned short hu[4], lu[4];
    #pragma unroll
    for (int i = 0; i < 4; i++){
      __hip_bfloat16 h = __float2bfloat16(xsv[i]);
      float hf = __bfloat162float(h);
      __hip_bfloat16 l = __float2bfloat16(xsv[i] - hf);
      hu[i] = *(unsigned short*)&h;
      lu[i] = *(unsigned short*)&l;
    }
    ushort4 hv = {hu[0], hu[1], hu[2], hu[3]};
    ushort4 lv = {lu[0], lu[1], lu[2], lu[3]};
    ushort4* row = (ushort4*)(Y + (size_t)m*KTOT);
    int s = k >> 2;
    if (mode == 0){ row[s] = hv; row[s+192] = hv; row[s+384] = lv; }
    else          { row[s] = hv; row[s+192] = lv; row[s+384] = hv; }
    return;
  }
  // ---- q path: one block per q row ----
  __shared__ float xrow[D_MODEL];
  __shared__ float yrow[D_MODEL];
  __shared__ float ws1[3], ws2[3];
  int r = b - (MPAD + D_MODEL);
  *(float4*)&xrow[t*4] = *(const float4*)&qx[r*D_MODEL + t*4];
  __syncthreads();
  float yv[4];
  #pragma unroll
  for (int c4 = 0; c4 < 4; c4++){
    int c = t + 192*c4;
    const float* wr = qw + (size_t)c*D_MODEL;
    float a = 0.f;
    for (int k = 0; k < D_MODEL; k += 4){
      float4 w4 = *(const float4*)&wr[k];
      a += xrow[k]*w4.x + xrow[k+1]*w4.y + xrow[k+2]*w4.z + xrow[k+3]*w4.w;
    }
    yv[c4] = a + qb[c];
    yrow[c] = yv[c4];
  }
  // LN reduction across 192 threads (3 waves)
  float s1 = yv[0]+yv[1]+yv[2]+yv[3];
  float s2 = yv[0]*yv[0]+yv[1]*yv[1]+yv[2]*yv[2]+yv[3]*yv[3];
  for (int off = 32; off >= 1; off >>= 1){
    s1 += __shfl_xor(s1, off);
    s2 += __shfl_xor(s2, off);
  }
  int wave = t >> 6, lane = t & 63;
  if (lane == 0){ ws1[wave] = s1; ws2[wave] = s2; }
  __syncthreads();
  float S1 = ws1[0]+ws1[1]+ws1[2];
  float S2 = ws2[0]+ws2[1]+ws2[2];
  float mean = S1*(1.f/768.f);
  float var  = S2*(1.f/768.f) - mean*mean;
  float inv  = rsqrtf(var + LN_EPSF);
  #pragma unroll
  for (int c4 = 0; c4 < 4; c4++){
    int c = t + 192*c4;
    qln[r*D_MODEL + c] = (yrow[c]-mean)*inv*lnqw[c] + lnqb[c];
  }
}

// ---------------------------------------------------------------------------
// bf16 MFMA GEMM: C[kt][m][n] partial over K-split (kt = 0..2).
// 128x128 tile, BK=64, 256 thr = 4 waves (2x2 of 64x64), 16x16x32 MFMA.
// LDS slots xor-swizzled (kg ^= row&7) via per-lane GLOBAL source address.
// ---------------------------------------------------------------------------
__global__ __launch_bounds__(256) void gemm_mfma_kernel(
    const __hip_bfloat16* __restrict__ Ab, const __hip_bfloat16* __restrict__ Wb,
    float* __restrict__ Cp)
{
  __shared__ __hip_bfloat16 As[BM*BK];   // 16 KB
  __shared__ __hip_bfloat16 Bs[BN*BK];   // 16 KB
  int tid = threadIdx.x;
  int wave = tid >> 6, lane = tid & 63;
  int m0 = blockIdx.x*BM, n0 = blockIdx.y*BN, kt = blockIdx.z;
  int wr = wave >> 1, wc = wave & 1;

  float4v acc[4][4];
  #pragma unroll
  for (int i = 0; i < 4; i++)
    #pragma unroll
    for (int j = 0; j < 4; j++)
      acc[i][j] = (float4v){0.f, 0.f, 0.f, 0.f};

  int sbase = wave*256;
  for (int st = 0; st < KPER/BK; ++st){
    int k0 = kt*KPER + st*BK;
    __syncthreads();
    #pragma unroll
    for (int i = 0; i < 4; i++){
      int s  = sbase + i*64 + lane;
      int r  = s >> 3, kg = s & 7;
      int kgg = kg ^ (r & 7);
      gload16(Ab + (size_t)(m0 + r)*KTOT + k0 + kgg*8, (char*)As + (size_t)s*16);
      gload16(Wb + (size_t)(n0 + r)*KTOT + k0 + kgg*8, (char*)Bs + (size_t)s*16);
    }
    __syncthreads();
    #pragma unroll
    for (int ks = 0; ks < 2; ks++){
      int kq = ks*4 + (lane >> 4);
      short8v af[4], bf[4];
      #pragma unroll
      for (int t = 0; t < 4; t++){
        int ar = wr*64 + t*16 + (lane & 15);
        int as_ = ar*8 + (kq ^ (ar & 7));
        af[t] = *(const short8v*)((const char*)As + (size_t)as_*16);
        int br = wc*64 + t*16 + (lane & 15);
        int bs_ = br*8 + (kq ^ (br & 7));
        bf[t] = *(const short8v*)((const char*)Bs + (size_t)bs_*16);
      }
      #pragma unroll
      for (int i = 0; i < 4; i++)
        #pragma unroll
        for (int j = 0; j < 4; j++)
          acc[i][j] = __builtin_amdgcn_mfma_f32_16x16x32_bf16(af[i], bf[j], acc[i][j], 0, 0, 0);
    }
  }

  float* C = Cp + (size_t)kt*MKV*D_MODEL;
  #pragma unroll
  for (int i = 0; i < 4; i++){
    int mb = m0 + wr*64 + i*16 + ((lane >> 4) << 2);
    #pragma unroll
    for (int j = 0; j < 4; j++){
      int n = n0 + wc*64 + j*16 + (lane & 15);
      #pragma unroll
      for (int r = 0; r < 4; r++){
        int m = mb + r;
        if (m < MKV) C[(size_t)m*D_MODEL + n] = acc[i][j][r];
      }
    }
  }
}

// ---------------------------------------------------------------------------
// LN over y0+y1+y2+bias (sums the 3 split-K GEMM partials)
// ---------------------------------------------------------------------------
__global__ __launch_bounds__(256) void ln_rows3_kernel(
    const float* __restrict__ Y0, const float* __restrict__ Y1,
    const float* __restrict__ Y2, const float* __restrict__ bias,
    const float* __restrict__ lnw, const float* __restrict__ lnb,
    float* __restrict__ out)
{
  __shared__ float red[256], red2[256];
  int r = blockIdx.x, tid = threadIdx.x;
  const float* y0 = Y0 + (size_t)r*D_MODEL;
  const float* y1 = Y1 + (size_t)r*D_MODEL;
  const float* y2 = Y2 + (size_t)r*D_MODEL;
  float x0 = y0[tid      ] + y1[tid      ] + y2[tid      ] + bias[tid      ];
  float x1 = y0[tid + 256] + y1[tid + 256] + y2[tid + 256] + bias[tid + 256];
  float x2 = y0[tid + 512] + y1[tid + 512] + y2[tid + 512] + bias[tid + 512];
  red[tid] = x0 + x1 + x2; red2[tid] = x0*x0 + x1*x1 + x2*x2;
  __syncthreads();
  for (int st = 128; st > 0; st >>= 1){
    if (tid < st){ red[tid] += red[tid+st]; red2[tid] += red2[tid+st]; }
    __syncthreads();
  }
  float mean = red[0]*(1.f/768.f);
  float var  = red2[0]*(1.f/768.f) - mean*mean;
  float inv  = rsqrtf(var + LN_EPSF);
  float* orow = out + (size_t)r*D_MODEL;
  orow[tid      ] = (x0-mean)*inv*lnw[tid      ] + lnb[tid      ];
  orow[tid + 256] = (x1-mean)*inv*lnw[tid + 256] + lnb[tid + 256];
  orow[tid + 512] = (x2-mean)*inv*lnw[tid + 512] + lnb[tid + 512];
}

// ---------------------------------------------------------------------------
// Fused per-(rank, head) attention partials + out_w projection.
// For half = 0,1 sequentially (A-tile LDS reused):
//   A[p,d] = kv_ln[r,p,h,d] + pos[half*197+p, h,d]
//   s[q,p] = SCALE * <q_ln[q,h,:], A[p,:]>;  m,Z online-softmax partials
//   U[half*8+q][d] = sum_p exp(s-m) * A[p,d]   (kept in LDS)
// Then projection phase: P{1,2}[r,h,q,n] = U[.][:] @ out_w[n, h*64:]^T
// Grid (16,12), 256 threads.  LDS = 63.7 KB.
// ---------------------------------------------------------------------------
__global__ __launch_bounds__(256) void rank_proj_kernel(
    const float* __restrict__ kv_ln, const float* __restrict__ q_ln,
    const float* __restrict__ ppe, const float* __restrict__ ow,
    float* __restrict__ m1O, float* __restrict__ z1O,
    float* __restrict__ m2O, float* __restrict__ z2O,
    float* __restrict__ p1, float* __restrict__ p2)
{
  __shared__ float A[PP*65];       // 51.2 KB
  __shared__ float qs[NQR*64];     //  2.0 KB
  __shared__ float E[NQR*PP];      //  6.3 KB
  __shared__ float Us[16*64];      //  4.1 KB
  int r = blockIdx.x, h = blockIdx.y;
  int tid = threadIdx.x;

  for (int e = tid; e < NQR*64; e += 256){
    int q = e >> 6, d = e & 63;
    qs[e] = q_ln[q*D_MODEL + h*64 + d];
  }

  for (int half = 0; half < 2; half++){
    __syncthreads();   // prior-half A/E reads complete before overwrite
    for (int e = tid; e < PP*64; e += 256){
      int p = e >> 6, d = e & 63;
      A[p*65 + d] = kv_ln[((size_t)(r*PP + p))*D_MODEL + h*64 + d]
                  + ppe[((size_t)(half*PP + p))*D_MODEL + h*64 + d];
    }
    __syncthreads();

    int q = tid >> 5, sub = tid & 31;
    float s[7];
    #pragma unroll
    for (int i = 0; i < 7; i++) s[i] = 0.f;
    for (int d = 0; d < 64; d++){
      float qv = qs[q*64 + d];
      #pragma unroll
      for (int i = 0; i < 7; i++){
        int p = sub + 32*i;
        int pc = p < PP ? p : PP-1;
        s[i] += qv * A[pc*65 + d];
      }
    }
    float mloc = -1e30f;
    #pragma unroll
    for (int i = 0; i < 7; i++){
      int p = sub + 32*i;
      s[i] = (p < PP) ? s[i]*SCALEF : -1e30f;
      mloc = fmaxf(mloc, s[i]);
    }
    for (int off = 16; off >= 1; off >>= 1)
      mloc = fmaxf(mloc, __shfl_xor(mloc, off, 32));
    float zloc = 0.f;
    #pragma unroll
    for (int i = 0; i < 7; i++){
      int p = sub + 32*i;
      float e = __expf(s[i] - mloc);
      if (p < PP){ E[q*PP + p] = e; zloc += e; }
    }
    for (int off = 16; off >= 1; off >>= 1)
      zloc += __shfl_xor(zloc, off, 32);

    int idx = (r*NHEADS + h)*NQR + q;
    if (sub == 0){
      if (half){ m2O[idx] = mloc; z2O[idx] = zloc; }
      else     { m1O[idx] = mloc; z1O[idx] = zloc; }
    }
    __syncthreads();

    float u0 = 0.f, u1 = 0.f;
    for (int p = 0; p < PP; p++){
      float e = E[q*PP + p];
      u0 += e * A[p*65 + sub];
      u1 += e * A[p*65 + sub + 32];
    }
    Us[(half*NQR + q)*64 + sub]      = u0;
    Us[(half*NQR + q)*64 + sub + 32] = u1;
  }
  __syncthreads();

  // ---- projection phase: P[m16][n] = sum_d Us[m16][d] * ow[n][h*64+d] ----
  // thread owns n = tid, tid+256, tid+512 for all 16 rows.
  float acc[16][3];
  #pragma unroll
  for (int m = 0; m < 16; m++){ acc[m][0]=0.f; acc[m][1]=0.f; acc[m][2]=0.f; }
  const float* owh = ow + h*64;
  for (int d4 = 0; d4 < 64; d4 += 4){
    float4 w0 = *(const float4*)&owh[(size_t)(tid      )*D_MODEL + d4];
    float4 w1 = *(const float4*)&owh[(size_t)(tid + 256)*D_MODEL + d4];
    float4 w2 = *(const float4*)&owh[(size_t)(tid + 512)*D_MODEL + d4];
    #pragma unroll
    for (int m = 0; m < 16; m++){
      float4 u = *(const float4*)&Us[m*64 + d4];
      acc[m][0] += u.x*w0.x + u.y*w0.y + u.z*w0.z + u.w*w0.w;
      acc[m][1] += u.x*w1.x + u.y*w1.y + u.z*w1.z + u.w*w1.w;
      acc[m][2] += u.x*w2.x + u.y*w2.y + u.z*w2.z + u.w*w2.w;
    }
  }
  #pragma unroll
  for (int q = 0; q < NQR; q++){
    size_t base = (((size_t)r*NHEADS + h)*NQR + q)*D_MODEL;
    #pragma unroll
    for (int j = 0; j < 3; j++){
      p1[base + tid + 256*j] = acc[q][j];
      p2[base + tid + 256*j] = acc[8 + q][j];
    }
  }
}

// ---------------------------------------------------------------------------
// Final combine:
//   out[(i*16+j)*8+q, n] = sum_h c1[h]*P1[i,h,q,n] - c2[h]*P2[j,h,q,n] + out_b[n]
// ---------------------------------------------------------------------------
__global__ __launch_bounds__(256) void combine_out_kernel(
    const float* __restrict__ m1, const float* __restrict__ z1,
    const float* __restrict__ m2, const float* __restrict__ z2,
    const float* __restrict__ p1, const float* __restrict__ p2,
    const float* __restrict__ out_b, float* __restrict__ out)
{
  __shared__ float c1s[NHEADS], c2s[NHEADS];
  int pair = blockIdx.x, q = blockIdx.y, tid = threadIdx.x;
  int i = pair >> 4, j = pair & 15;
  if (tid < NHEADS){
    int h = tid;
    int ii = (i*NHEADS + h)*NQR + q;
    int jj = (j*NHEADS + h)*NQR + q;
    float mi = m1[ii], mj = m2[jj];
    float mm = fmaxf(mi, mj);
    float a1 = __expf(mi - mm), a2 = __expf(mj - mm);
    float rden = 1.f / (a1*z1[ii] + a2*z2[jj]);
    c1s[h] = a1*rden; c2s[h] = a2*rden;
  }
  __syncthreads();
  float* orow = out + ((size_t)(pair*NQR + q))*D_MODEL;
  for (int nn = tid; nn < D_MODEL; nn += 256){
    float acc = out_b[nn];
    #pragma unroll
    for (int h = 0; h < NHEADS; h++){
      acc += c1s[h]*p1[(((size_t)i*NHEADS + h)*NQR + q)*D_MODEL + nn]
           - c2s[h]*p2[(((size_t)j*NHEADS + h)*NQR + q)*D_MODEL + nn];
    }
    orow[nn] = acc;
  }
}

// ---------------------------------------------------------------------------
extern "C" void kernel_launch(void* const* d_in, const int* in_sizes, int n_in,
                              void* d_out, int out_size, void* d_ws, size_t ws_size,
                              hipStream_t stream)
{
  const float* q_x    = (const float*)d_in[0];
  const float* kv_x   = (const float*)d_in[1];
  const float* ppe    = (const float*)d_in[2];
  const float* q_w    = (const float*)d_in[3];
  const float* q_b    = (const float*)d_in[4];
  const float* kv_w   = (const float*)d_in[5];
  const float* kv_b   = (const float*)d_in[6];
  const float* out_w  = (const float*)d_in[7];
  const float* out_b  = (const float*)d_in[8];
  const float* lnq_w  = (const float*)d_in[9];
  const float* lnq_b  = (const float*)d_in[10];
  const float* lnkv_w = (const float*)d_in[11];
  const float* lnkv_b = (const float*)d_in[12];
  float* out = (float*)d_out;

  // workspace (f32 units). Aliasing by lifetime:
  //   Abuf (bf16, dead after gemm)  <- later kv_ln
  //   Wbuf (bf16, dead after gemm)  <- later m/z partials
  //   C0..C2 (gemm partials, dead after ln3) <- later p1,p2
  float* ws    = (float*)d_ws;
  float* q_ln  = ws;                              //  6144
  float* Abuf_f = q_ln + NQR*D_MODEL;             //  3,686,400 (3200*2304 bf16)
  float* Wbuf_f = Abuf_f + (size_t)MPAD*KTOT/2;   //    884,736 (768*2304 bf16)
  float* C0    = Wbuf_f + (size_t)D_MODEL*KTOT/2; //  3x 2,420,736
  float* C1    = C0 + (size_t)MKV*D_MODEL;
  float* C2    = C1 + (size_t)MKV*D_MODEL;

  __hip_bfloat16* Abuf = (__hip_bfloat16*)Abuf_f;
  __hip_bfloat16* Wbuf = (__hip_bfloat16*)Wbuf_f;

  float* kv_ln = Abuf_f;                          // alias (2,420,736 <= 3,686,400)
  float* m1    = Wbuf_f;                          // alias region (6,144 <= 884,736)
  float* z1    = m1 + BB*NHEADS*NQR;
  float* m2    = z1 + BB*NHEADS*NQR;
  float* z2    = m2 + BB*NHEADS*NQR;
  float* p1    = C0;                              // alias (2,359,296 <= 7,262,208)
  float* p2    = p1 + (size_t)BB*NHEADS*NQR*D_MODEL;

  pack_q_kernel<<<MPAD + D_MODEL + NQR, 192, 0, stream>>>(
      kv_x, kv_w, Abuf, Wbuf, q_x, q_w, q_b, lnq_w, lnq_b, q_ln);

  gemm_mfma_kernel<<<dim3(MPAD/BM, D_MODEL/BN, KSPLIT), 256, 0, stream>>>(
      Abuf, Wbuf, C0);

  ln_rows3_kernel<<<MKV, 256, 0, stream>>>(C0, C1, C2, kv_b, lnkv_w, lnkv_b, kv_ln);

  rank_proj_kernel<<<dim3(BB, NHEADS), 256, 0, stream>>>(
      kv_ln, q_ln, ppe, out_w, m1, z1, m2, z2, p1, p2);

  combine_out_kernel<<<dim3(NPAIR, NQR), 256, 0, stream>>>(
      m1, z1, m2, z2, p1, p2, out_b, out);
}

// Round 6
// 180.927 us; speedup vs baseline: 1.3386x; 1.3386x over previous
//
#include <hip/hip_runtime.h>
#include <hip/hip_bf16.h>
#include <math.h>

#define D_MODEL 768
#define NHEADS  12
#define DHEAD   64
#define NQR     8     // query rows
#define BB      16    // batch (ranks)
#define PP      197   // tokens per rank
#define NPAIR   256   // BB*BB
#define MKV     (BB*PP)     // 3152
#define LN_EPSF 1e-5f
#define SCALEF  0.125f      // 64^-0.5

// split-bf16 K-extended GEMM params
#define KTOT  2304          // 3*768:  [a_hi|a_hi|a_lo] x [w_hi|w_lo|w_hi]
#define KSPLIT 3
#define KPER  (KTOT/KSPLIT) // 768
#define MPAD  3200          // 25*128
#define BM 128
#define BN 128
#define BK 64

typedef __attribute__((ext_vector_type(8))) short short8v;   // 8 bf16
typedef __attribute__((ext_vector_type(4))) float float4v;   // mfma acc

__device__ __forceinline__ void gload16(const void* g, void* l){
  __builtin_amdgcn_global_load_lds(
      (const __attribute__((address_space(1))) unsigned int*)g,
      (__attribute__((address_space(3))) unsigned int*)l, 16, 0, 0);
}

// ---------------------------------------------------------------------------
// q GEMM: qy[8,768] = qx[8,768] @ qw[768,768]^T
// 96 blocks x 256 thr; 8 cols/block x 32 lanes/col (coalesced w-row reads).
// NOTE (R5 post-mortem): do NOT replace with per-thread serial dot — the
// lane-strided weight-row pattern is latency-bound (75+ us for 8 rows).
// ---------------------------------------------------------------------------
__global__ __launch_bounds__(256) void qgemm_kernel(
    const float* __restrict__ qx, const float* __restrict__ qw,
    float* __restrict__ qy)
{
  __shared__ float xs[NQR*D_MODEL];
  int tid = threadIdx.x;
  for (int e = tid*4; e < NQR*D_MODEL; e += 1024)
    *(float4*)&xs[e] = *(const float4*)&qx[e];
  __syncthreads();
  int col = tid >> 5, lane = tid & 31;
  int c = blockIdx.x*8 + col;
  const float* wr = qw + (size_t)c*D_MODEL;
  float acc[NQR] = {};
  for (int k = lane*4; k < D_MODEL; k += 128){
    float4 w4 = *(const float4*)&wr[k];
    #pragma unroll
    for (int q = 0; q < NQR; q++){
      float4 x4 = *(const float4*)&xs[q*D_MODEL + k];
      acc[q] += x4.x*w4.x + x4.y*w4.y + x4.z*w4.z + x4.w*w4.w;
    }
  }
  #pragma unroll
  for (int q = 0; q < NQR; q++){
    float a = acc[q];
    for (int off = 16; off >= 1; off >>= 1) a += __shfl_xor(a, off, 32);
    if (lane == 0) qy[q*D_MODEL + c] = a;
  }
}

// ---------------------------------------------------------------------------
// LN over y+bias (q path, 8 rows)
// ---------------------------------------------------------------------------
__global__ __launch_bounds__(256) void ln_rows_kernel(
    const float* __restrict__ Y, const float* __restrict__ bias,
    const float* __restrict__ lnw, const float* __restrict__ lnb,
    float* __restrict__ out)
{
  __shared__ float red[256], red2[256];
  int r = blockIdx.x, tid = threadIdx.x;
  const float* yr = Y + (size_t)r*D_MODEL;
  float x0 = yr[tid      ] + bias[tid      ];
  float x1 = yr[tid + 256] + bias[tid + 256];
  float x2 = yr[tid + 512] + bias[tid + 512];
  red[tid] = x0 + x1 + x2; red2[tid] = x0*x0 + x1*x1 + x2*x2;
  __syncthreads();
  for (int st = 128; st > 0; st >>= 1){
    if (tid < st){ red[tid] += red[tid+st]; red2[tid] += red2[tid+st]; }
    __syncthreads();
  }
  float mean = red[0]*(1.f/768.f);
  float var  = red2[0]*(1.f/768.f) - mean*mean;
  float inv  = rsqrtf(var + LN_EPSF);
  float* orow = out + (size_t)r*D_MODEL;
  orow[tid      ] = (x0-mean)*inv*lnw[tid      ] + lnb[tid      ];
  orow[tid + 256] = (x1-mean)*inv*lnw[tid + 256] + lnb[tid + 256];
  orow[tid + 512] = (x2-mean)*inv*lnw[tid + 512] + lnb[tid + 512];
}

// ---------------------------------------------------------------------------
// fused pack: f32 row [768] -> bf16 row [2304] as three 768-segments.
// blocks [0, MPAD)        : activations (kv_x), layout [hi, hi, lo]
// blocks [MPAD, MPAD+768) : weights (kv_w),     layout [hi, lo, hi]
// ---------------------------------------------------------------------------
__global__ __launch_bounds__(192) void pack_both_kernel(
    const float* __restrict__ kvx, const float* __restrict__ kvw,
    __hip_bfloat16* __restrict__ Ab, __hip_bfloat16* __restrict__ Wb)
{
  int b = blockIdx.x, t = threadIdx.x;
  const float* X; __hip_bfloat16* Y; int valid, mode, m;
  if (b < MPAD){ X = kvx; Y = Ab; valid = MKV;     mode = 0; m = b; }
  else         { X = kvw; Y = Wb; valid = D_MODEL; mode = 1; m = b - MPAD; }
  int k = t*4;
  float4 v = (m < valid) ? *(const float4*)&X[(size_t)m*D_MODEL + k]
                         : make_float4(0.f,0.f,0.f,0.f);
  float xsv[4] = {v.x, v.y, v.z, v.w};
  unsigned short hu[4], lu[4];
  #pragma unroll
  for (int i = 0; i < 4; i++){
    __hip_bfloat16 h = __float2bfloat16(xsv[i]);
    float hf = __bfloat162float(h);
    __hip_bfloat16 l = __float2bfloat16(xsv[i] - hf);
    hu[i] = *(unsigned short*)&h;
    lu[i] = *(unsigned short*)&l;
  }
  ushort4 hv = {hu[0], hu[1], hu[2], hu[3]};
  ushort4 lv = {lu[0], lu[1], lu[2], lu[3]};
  ushort4* row = (ushort4*)(Y + (size_t)m*KTOT);
  int s = k >> 2;
  if (mode == 0){ row[s] = hv; row[s+192] = hv; row[s+384] = lv; }
  else          { row[s] = hv; row[s+192] = lv; row[s+384] = hv; }
}

// ---------------------------------------------------------------------------
// bf16 MFMA GEMM: C[kt][m][n] partial over K-split (kt = 0..2).
// 128x128 tile, BK=64, 256 thr = 4 waves (2x2 of 64x64), 16x16x32 MFMA.
// LDS slots xor-swizzled (kg ^= row&7) via per-lane GLOBAL source address.
// ---------------------------------------------------------------------------
__global__ __launch_bounds__(256) void gemm_mfma_kernel(
    const __hip_bfloat16* __restrict__ Ab, const __hip_bfloat16* __restrict__ Wb,
    float* __restrict__ Cp)
{
  __shared__ __hip_bfloat16 As[BM*BK];   // 16 KB
  __shared__ __hip_bfloat16 Bs[BN*BK];   // 16 KB
  int tid = threadIdx.x;
  int wave = tid >> 6, lane = tid & 63;
  int m0 = blockIdx.x*BM, n0 = blockIdx.y*BN, kt = blockIdx.z;
  int wr = wave >> 1, wc = wave & 1;

  float4v acc[4][4];
  #pragma unroll
  for (int i = 0; i < 4; i++)
    #pragma unroll
    for (int j = 0; j < 4; j++)
      acc[i][j] = (float4v){0.f, 0.f, 0.f, 0.f};

  int sbase = wave*256;
  for (int st = 0; st < KPER/BK; ++st){
    int k0 = kt*KPER + st*BK;
    __syncthreads();
    #pragma unroll
    for (int i = 0; i < 4; i++){
      int s  = sbase + i*64 + lane;
      int r  = s >> 3, kg = s & 7;
      int kgg = kg ^ (r & 7);
      gload16(Ab + (size_t)(m0 + r)*KTOT + k0 + kgg*8, (char*)As + (size_t)s*16);
      gload16(Wb + (size_t)(n0 + r)*KTOT + k0 + kgg*8, (char*)Bs + (size_t)s*16);
    }
    __syncthreads();
    #pragma unroll
    for (int ks = 0; ks < 2; ks++){
      int kq = ks*4 + (lane >> 4);
      short8v af[4], bf[4];
      #pragma unroll
      for (int t = 0; t < 4; t++){
        int ar = wr*64 + t*16 + (lane & 15);
        int as_ = ar*8 + (kq ^ (ar & 7));
        af[t] = *(const short8v*)((const char*)As + (size_t)as_*16);
        int br = wc*64 + t*16 + (lane & 15);
        int bs_ = br*8 + (kq ^ (br & 7));
        bf[t] = *(const short8v*)((const char*)Bs + (size_t)bs_*16);
      }
      #pragma unroll
      for (int i = 0; i < 4; i++)
        #pragma unroll
        for (int j = 0; j < 4; j++)
          acc[i][j] = __builtin_amdgcn_mfma_f32_16x16x32_bf16(af[i], bf[j], acc[i][j], 0, 0, 0);
    }
  }

  float* C = Cp + (size_t)kt*MKV*D_MODEL;
  #pragma unroll
  for (int i = 0; i < 4; i++){
    int mb = m0 + wr*64 + i*16 + ((lane >> 4) << 2);
    #pragma unroll
    for (int j = 0; j < 4; j++){
      int n = n0 + wc*64 + j*16 + (lane & 15);
      #pragma unroll
      for (int r = 0; r < 4; r++){
        int m = mb + r;
        if (m < MKV) C[(size_t)m*D_MODEL + n] = acc[i][j][r];
      }
    }
  }
}

// ---------------------------------------------------------------------------
// LN over y0+y1+y2+bias (sums the 3 split-K GEMM partials)
// ---------------------------------------------------------------------------
__global__ __launch_bounds__(256) void ln_rows3_kernel(
    const float* __restrict__ Y0, const float* __restrict__ Y1,
    const float* __restrict__ Y2, const float* __restrict__ bias,
    const float* __restrict__ lnw, const float* __restrict__ lnb,
    float* __restrict__ out)
{
  __shared__ float red[256], red2[256];
  int r = blockIdx.x, tid = threadIdx.x;
  const float* y0 = Y0 + (size_t)r*D_MODEL;
  const float* y1 = Y1 + (size_t)r*D_MODEL;
  const float* y2 = Y2 + (size_t)r*D_MODEL;
  float x0 = y0[tid      ] + y1[tid      ] + y2[tid      ] + bias[tid      ];
  float x1 = y0[tid + 256] + y1[tid + 256] + y2[tid + 256] + bias[tid + 256];
  float x2 = y0[tid + 512] + y1[tid + 512] + y2[tid + 512] + bias[tid + 512];
  red[tid] = x0 + x1 + x2; red2[tid] = x0*x0 + x1*x1 + x2*x2;
  __syncthreads();
  for (int st = 128; st > 0; st >>= 1){
    if (tid < st){ red[tid] += red[tid+st]; red2[tid] += red2[tid+st]; }
    __syncthreads();
  }
  float mean = red[0]*(1.f/768.f);
  float var  = red2[0]*(1.f/768.f) - mean*mean;
  float inv  = rsqrtf(var + LN_EPSF);
  float* orow = out + (size_t)r*D_MODEL;
  orow[tid      ] = (x0-mean)*inv*lnw[tid      ] + lnb[tid      ];
  orow[tid + 256] = (x1-mean)*inv*lnw[tid + 256] + lnb[tid + 256];
  orow[tid + 512] = (x2-mean)*inv*lnw[tid + 512] + lnb[tid + 512];
}

// ---------------------------------------------------------------------------
// Fused per-(rank, head) attention partials + out_w projection.
// For half = 0,1 sequentially (A-tile LDS reused):
//   A[p,d] = kv_ln[r,p,h,d] + pos[half*197+p, h,d]
//   s[q,p] = SCALE * <q_ln[q,h,:], A[p,:]>;  m,Z online-softmax partials
//   U[half*8+q][d] = sum_p exp(s-m) * A[p,d]   (kept in LDS)
// Then projection: P{1,2}[r,h,q,n] = U[.][:] @ out_w[n, h*64:]^T
// Grid (16,12), 256 threads.  LDS = 63.7 KB.
// ---------------------------------------------------------------------------
__global__ __launch_bounds__(256) void rank_proj_kernel(
    const float* __restrict__ kv_ln, const float* __restrict__ q_ln,
    const float* __restrict__ ppe, const float* __restrict__ ow,
    float* __restrict__ m1O, float* __restrict__ z1O,
    float* __restrict__ m2O, float* __restrict__ z2O,
    float* __restrict__ p1, float* __restrict__ p2)
{
  __shared__ float A[PP*65];       // 51.2 KB
  __shared__ float qs[NQR*64];     //  2.0 KB
  __shared__ float E[NQR*PP];      //  6.3 KB
  __shared__ float Us[16*64];      //  4.1 KB
  int r = blockIdx.x, h = blockIdx.y;
  int tid = threadIdx.x;

  for (int e = tid; e < NQR*64; e += 256){
    int q = e >> 6, d = e & 63;
    qs[e] = q_ln[q*D_MODEL + h*64 + d];
  }

  for (int half = 0; half < 2; half++){
    __syncthreads();
    for (int e = tid; e < PP*64; e += 256){
      int p = e >> 6, d = e & 63;
      A[p*65 + d] = kv_ln[((size_t)(r*PP + p))*D_MODEL + h*64 + d]
                  + ppe[((size_t)(half*PP + p))*D_MODEL + h*64 + d];
    }
    __syncthreads();

    int q = tid >> 5, sub = tid & 31;
    float s[7];
    #pragma unroll
    for (int i = 0; i < 7; i++) s[i] = 0.f;
    for (int d = 0; d < 64; d++){
      float qv = qs[q*64 + d];
      #pragma unroll
      for (int i = 0; i < 7; i++){
        int p = sub + 32*i;
        int pc = p < PP ? p : PP-1;
        s[i] += qv * A[pc*65 + d];
      }
    }
    float mloc = -1e30f;
    #pragma unroll
    for (int i = 0; i < 7; i++){
      int p = sub + 32*i;
      s[i] = (p < PP) ? s[i]*SCALEF : -1e30f;
      mloc = fmaxf(mloc, s[i]);
    }
    for (int off = 16; off >= 1; off >>= 1)
      mloc = fmaxf(mloc, __shfl_xor(mloc, off, 32));
    float zloc = 0.f;
    #pragma unroll
    for (int i = 0; i < 7; i++){
      int p = sub + 32*i;
      float e = __expf(s[i] - mloc);
      if (p < PP){ E[q*PP + p] = e; zloc += e; }
    }
    for (int off = 16; off >= 1; off >>= 1)
      zloc += __shfl_xor(zloc, off, 32);

    int idx = (r*NHEADS + h)*NQR + q;
    if (sub == 0){
      if (half){ m2O[idx] = mloc; z2O[idx] = zloc; }
      else     { m1O[idx] = mloc; z1O[idx] = zloc; }
    }
    __syncthreads();

    float u0 = 0.f, u1 = 0.f;
    for (int p = 0; p < PP; p++){
      float e = E[q*PP + p];
      u0 += e * A[p*65 + sub];
      u1 += e * A[p*65 + sub + 32];
    }
    Us[(half*NQR + q)*64 + sub]      = u0;
    Us[(half*NQR + q)*64 + sub + 32] = u1;
  }
  __syncthreads();

  // ---- projection: P[m16][n] = sum_d Us[m16][d] * ow[n][h*64+d] ----
  float acc[16][3];
  #pragma unroll
  for (int m = 0; m < 16; m++){ acc[m][0]=0.f; acc[m][1]=0.f; acc[m][2]=0.f; }
  const float* owh = ow + h*64;
  for (int d4 = 0; d4 < 64; d4 += 4){
    float4 w0 = *(const float4*)&owh[(size_t)(tid      )*D_MODEL + d4];
    float4 w1 = *(const float4*)&owh[(size_t)(tid + 256)*D_MODEL + d4];
    float4 w2 = *(const float4*)&owh[(size_t)(tid + 512)*D_MODEL + d4];
    #pragma unroll
    for (int m = 0; m < 16; m++){
      float4 u = *(const float4*)&Us[m*64 + d4];
      acc[m][0] += u.x*w0.x + u.y*w0.y + u.z*w0.z + u.w*w0.w;
      acc[m][1] += u.x*w1.x + u.y*w1.y + u.z*w1.z + u.w*w1.w;
      acc[m][2] += u.x*w2.x + u.y*w2.y + u.z*w2.z + u.w*w2.w;
    }
  }
  #pragma unroll
  for (int q = 0; q < NQR; q++){
    size_t base = (((size_t)r*NHEADS + h)*NQR + q)*D_MODEL;
    #pragma unroll
    for (int j = 0; j < 3; j++){
      p1[base + tid + 256*j] = acc[q][j];
      p2[base + tid + 256*j] = acc[8 + q][j];
    }
  }
}

// ---------------------------------------------------------------------------
// Final combine:
//   out[(i*16+j)*8+q, n] = sum_h c1[h]*P1[i,h,q,n] - c2[h]*P2[j,h,q,n] + out_b[n]
// ---------------------------------------------------------------------------
__global__ __launch_bounds__(256) void combine_out_kernel(
    const float* __restrict__ m1, const float* __restrict__ z1,
    const float* __restrict__ m2, const float* __restrict__ z2,
    const float* __restrict__ p1, const float* __restrict__ p2,
    const float* __restrict__ out_b, float* __restrict__ out)
{
  __shared__ float c1s[NHEADS], c2s[NHEADS];
  int pair = blockIdx.x, q = blockIdx.y, tid = threadIdx.x;
  int i = pair >> 4, j = pair & 15;
  if (tid < NHEADS){
    int h = tid;
    int ii = (i*NHEADS + h)*NQR + q;
    int jj = (j*NHEADS + h)*NQR + q;
    float mi = m1[ii], mj = m2[jj];
    float mm = fmaxf(mi, mj);
    float a1 = __expf(mi - mm), a2 = __expf(mj - mm);
    float rden = 1.f / (a1*z1[ii] + a2*z2[jj]);
    c1s[h] = a1*rden; c2s[h] = a2*rden;
  }
  __syncthreads();
  float* orow = out + ((size_t)(pair*NQR + q))*D_MODEL;
  for (int nn = tid; nn < D_MODEL; nn += 256){
    float acc = out_b[nn];
    #pragma unroll
    for (int h = 0; h < NHEADS; h++){
      acc += c1s[h]*p1[(((size_t)i*NHEADS + h)*NQR + q)*D_MODEL + nn]
           - c2s[h]*p2[(((size_t)j*NHEADS + h)*NQR + q)*D_MODEL + nn];
    }
    orow[nn] = acc;
  }
}

// ---------------------------------------------------------------------------
extern "C" void kernel_launch(void* const* d_in, const int* in_sizes, int n_in,
                              void* d_out, int out_size, void* d_ws, size_t ws_size,
                              hipStream_t stream)
{
  const float* q_x    = (const float*)d_in[0];
  const float* kv_x   = (const float*)d_in[1];
  const float* ppe    = (const float*)d_in[2];
  const float* q_w    = (const float*)d_in[3];
  const float* q_b    = (const float*)d_in[4];
  const float* kv_w   = (const float*)d_in[5];
  const float* kv_b   = (const float*)d_in[6];
  const float* out_w  = (const float*)d_in[7];
  const float* out_b  = (const float*)d_in[8];
  const float* lnq_w  = (const float*)d_in[9];
  const float* lnq_b  = (const float*)d_in[10];
  const float* lnkv_w = (const float*)d_in[11];
  const float* lnkv_b = (const float*)d_in[12];
  float* out = (float*)d_out;

  // workspace (f32 units). Aliasing by lifetime:
  //   Abuf (bf16, dead after gemm)  <- later kv_ln
  //   Wbuf (bf16, dead after gemm)  <- later m/z partials
  //   C0..C2 (gemm partials, dead after ln3) <- later p1,p2
  float* ws    = (float*)d_ws;
  float* q_y   = ws;                              //  6144
  float* q_ln  = q_y  + NQR*D_MODEL;              //  6144
  float* Abuf_f = q_ln + NQR*D_MODEL;             //  3,686,400 (3200*2304 bf16)
  float* Wbuf_f = Abuf_f + (size_t)MPAD*KTOT/2;   //    884,736 (768*2304 bf16)
  float* C0    = Wbuf_f + (size_t)D_MODEL*KTOT/2; //  3x 2,420,736
  float* C1    = C0 + (size_t)MKV*D_MODEL;
  float* C2    = C1 + (size_t)MKV*D_MODEL;

  __hip_bfloat16* Abuf = (__hip_bfloat16*)Abuf_f;
  __hip_bfloat16* Wbuf = (__hip_bfloat16*)Wbuf_f;

  float* kv_ln = Abuf_f;                          // alias (2,420,736 <= 3,686,400)
  float* m1    = Wbuf_f;                          // alias region (6,144 <= 884,736)
  float* z1    = m1 + BB*NHEADS*NQR;
  float* m2    = z1 + BB*NHEADS*NQR;
  float* z2    = m2 + BB*NHEADS*NQR;
  float* p1    = C0;                              // alias (2,359,296 <= 7,262,208)
  float* p2    = p1 + (size_t)BB*NHEADS*NQR*D_MODEL;

  qgemm_kernel<<<96, 256, 0, stream>>>(q_x, q_w, q_y);
  ln_rows_kernel<<<NQR, 256, 0, stream>>>(q_y, q_b, lnq_w, lnq_b, q_ln);

  pack_both_kernel<<<MPAD + D_MODEL, 192, 0, stream>>>(kv_x, kv_w, Abuf, Wbuf);

  gemm_mfma_kernel<<<dim3(MPAD/BM, D_MODEL/BN, KSPLIT), 256, 0, stream>>>(
      Abuf, Wbuf, C0);

  ln_rows3_kernel<<<MKV, 256, 0, stream>>>(C0, C1, C2, kv_b, lnkv_w, lnkv_b, kv_ln);

  rank_proj_kernel<<<dim3(BB, NHEADS), 256, 0, stream>>>(
      kv_ln, q_ln, ppe, out_w, m1, z1, m2, z2, p1, p2);

  combine_out_kernel<<<dim3(NPAIR, NQR), 256, 0, stream>>>(
      m1, z1, m2, z2, p1, p2, out_b, out);
}